// Round 2
// baseline (104.444 us; speedup 1.0000x reference)
//
#include <hip/hip_runtime.h>

// IrrepsIndexedLinear: y_ir[n,o,i] = alpha * sum_m x_ir[n,m,i] * w[seg(n), ir, m, o]
// N=2048, MUL=128, dims {1,3,5}, G=32, alpha = 1/64.
//
// Round-4: revert to round-2's measured-good tiling (TR {32,16,8}, RP {4,6,5},
// 544-block layout) and attack the W path. Round 3 (TR=8 everywhere) regressed
// 93.6->98.5us because W bytes/FMA = 4/RP: streaming W from global per thread
// (16B/m) put ~221MB through the L1/L2 return path. Round 2 already paid
// ~139MB (~3.5us). Fix:
//  - W double-buffered through LDS in MC=16 m-chunks (8KB/chunk): unique 64KB
//    per block read ONCE from global (35MB total, L2-served), re-reads served
//    by the LDS pipe which is nearly idle (X reads are broadcasts).
//  - reg-staged prefetch (T14): global loads for chunk c+1 issued at top of
//    iter c, ds_write after the compute, ONE barrier per chunk (8 total).
//    HBM/L2 latency hides under 16 m's of FMA.
//  - W LDS reads: thread owns o = {to, to+32, to+64, to+96} -> b32 reads at
//    stride 32 floats = 2 lanes/bank broadcast pairs, conflict-free.
//  - per-output summation order (m ascending, fmac) identical to round 2 ->
//    bit-exact, absmax stays 0.0.
//  - LDS 24KB X + 16KB W = 40KB -> 4 blocks/CU, 16 waves/CU.

#define NGROUP 32
#define WSTRIDE (128 * 128 * 3) // floats per weight group
#define ALPHA 0.015625f         // 1/sqrt(32*128) = 1/64 exactly

// tile capacities: cap_ir = NGROUP + NROWS/TR_ir (worst case)
#define CAP0 96
#define CAP01 256
#define GRID_BLOCKS 544

#define XS_FLOATS 6144 // max TR*128*D: ir1 = 16*384 = 6144 (24 KB)
#define MC 16          // m's per W chunk
#define NCH 8          // 128 / MC
#define WCHUNK (MC * 128) // 2048 floats = 8 KB ; double-buffered = 16 KB

template <int D, int TR, int RP>
__device__ inline void run_ir(int lt, const float* __restrict__ x,
                              const float* __restrict__ w_base_ir, // w + ir off
                              const int* __restrict__ repeats,
                              float* __restrict__ obase, // out + ir out offset
                              float* __restrict__ Xs, float* __restrict__ Ws) {
  // ---- prefetch counts (uniform -> scalar loads, all in flight) ----
  int cnt[NGROUP];
#pragma unroll
  for (int gg = 0; gg < NGROUP; ++gg) cnt[gg] = repeats[gg];

  // ---- group-aligned tile lookup (uniform across block) ----
  int off = 0, g = -1, row0 = 0, nr = 0, tacc = 0;
#pragma unroll
  for (int gg = 0; gg < NGROUP; ++gg) {
    int c = cnt[gg];
    int tg = (c + TR - 1) / TR;
    if (g < 0 && lt < tacc + tg) {
      int tig = lt - tacc;
      g = gg;
      row0 = off + tig * TR;
      nr = min(TR, c - tig * TR);
    }
    tacc += tg;
    off += c;
  }
  if (g < 0) return; // beyond real tile count for this irrep (whole block)

  const int tid = threadIdx.x;
  const int to = tid & 31; // owns out columns o = to + 32*q, q=0..3
  const int tr = tid >> 5; // owns flat rows r = tr*RP .. tr*RP+RP-1

  constexpr int ROWELEMS = 128 * D;
  constexpr int BMELEMS = TR * ROWELEMS;

  // W source for this group+irrep: 16384 floats = 4096 float4, 16B-aligned
  const float4* wsrc = (const float4*)(w_base_ir + (size_t)g * WSTRIDE);

  // ---- issue W chunk 0 (2 float4 per thread) ----
  float4 wp0 = wsrc[tid];
  float4 wp1 = wsrc[256 + tid];

  // ---- stage X tile raw into LDS (straight float4 copy; zero-fill > nr) ----
  {
    const float4* xsrc = (const float4*)(x + (size_t)row0 * ROWELEMS);
    float4* xdst = (float4*)Xs;
    const int limit4 = nr * (ROWELEMS / 4);
    constexpr int Q = BMELEMS / 4; // 1024 / 1536 / 1280 -> multiple of 256
    const float4 z = make_float4(0.f, 0.f, 0.f, 0.f);
#pragma unroll
    for (int q = tid; q < Q; q += 256) xdst[q] = (q < limit4) ? xsrc[q] : z;
  }

  // ---- write W chunk 0 into buffer 0 ----
  {
    float4* wd = (float4*)Ws;
    wd[tid] = wp0;
    wd[256 + tid] = wp1;
  }
  __syncthreads();

  // ---- per-thread row constants: r = tr*RP + rr -> (n_loc, i) ----
  int xoff[RP];
  int nloc[RP];
  int iofr[RP];
#pragma unroll
  for (int rr = 0; rr < RP; ++rr) {
    int r = tr * RP + rr;
    int nl = r / D;
    int i = r - nl * D;
    nloc[rr] = nl;
    iofr[rr] = i;
    xoff[rr] = nl * ROWELEMS + i;
  }

  float acc[RP][4];
#pragma unroll
  for (int rr = 0; rr < RP; ++rr)
#pragma unroll
    for (int q = 0; q < 4; ++q) acc[rr][q] = 0.0f;

  // ---- K loop over 8 chunks of 16 m's; 1 barrier per chunk ----
  int cur = 0;
  for (int c = 0; c < NCH; ++c) {
    // prefetch next chunk into registers (in flight across the compute)
    if (c + 1 < NCH) {
      wp0 = wsrc[(c + 1) * 512 + tid];
      wp1 = wsrc[(c + 1) * 512 + 256 + tid];
    }
    const float* wsh = Ws + cur * WCHUNK + to;
    const float* xsh = Xs + c * (MC * D);
#pragma unroll
    for (int mm = 0; mm < MC; ++mm) {
      float wv[4];
#pragma unroll
      for (int q = 0; q < 4; ++q) wv[q] = wsh[mm * 128 + 32 * q];
      float xs[RP];
#pragma unroll
      for (int rr = 0; rr < RP; ++rr) xs[rr] = xsh[xoff[rr] + mm * D];
#pragma unroll
      for (int rr = 0; rr < RP; ++rr) {
        acc[rr][0] += xs[rr] * wv[0];
        acc[rr][1] += xs[rr] * wv[1];
        acc[rr][2] += xs[rr] * wv[2];
        acc[rr][3] += xs[rr] * wv[3];
      }
    }
    if (c + 1 < NCH) {
      // write prefetched chunk into the other buffer, then barrier
      float4* wd = (float4*)(Ws + (cur ^ 1) * WCHUNK);
      wd[tid] = wp0;
      wd[256 + tid] = wp1;
      __syncthreads();
      cur ^= 1;
    }
  }

  // ---- epilogue: y[n, o, i], o = to + 32*q ----
#pragma unroll
  for (int rr = 0; rr < RP; ++rr) {
    if (nloc[rr] < nr) {
      float* orow = obase + (size_t)(row0 + nloc[rr]) * ROWELEMS + iofr[rr];
#pragma unroll
      for (int q = 0; q < 4; ++q)
        orow[(to + 32 * q) * D] = acc[rr][q] * ALPHA;
    }
  }
}

__global__ __launch_bounds__(256, 4) void IrrepsIndexedLinear_39161511805249_kernel(
    const float* __restrict__ x0, const float* __restrict__ x1,
    const float* __restrict__ x2, const float* __restrict__ w,
    const int* __restrict__ repeats, float* __restrict__ out) {
  __shared__ float Xs[XS_FLOATS];    // 24 KB
  __shared__ float Ws[2 * WCHUNK];   // 16 KB

  const int bid = blockIdx.x;
  if (bid < CAP0) {
    // ir0: d=1, TR=32, RP=4 ; w offset 0 ; out offset 0
    run_ir<1, 32, 4>(bid, x0, w, repeats, out, Xs, Ws);
  } else if (bid < CAP01) {
    // ir1: d=3, TR=16, RP=6 ; w offset 16384 ; out offset 2048*128
    run_ir<3, 16, 6>(bid - CAP0, x1, w + 16384, repeats, out + 262144, Xs, Ws);
  } else {
    // ir2: d=5, TR=8, RP=5 ; w offset 32768 ; out offset 2048*128*4
    run_ir<5, 8, 5>(bid - CAP01, x2, w + 32768, repeats, out + 1048576, Xs, Ws);
  }
}

extern "C" void kernel_launch(void* const* d_in, const int* in_sizes, int n_in,
                              void* d_out, int out_size, void* d_ws, size_t ws_size,
                              hipStream_t stream) {
  const float* x0 = (const float*)d_in[0];
  const float* x1 = (const float*)d_in[1];
  const float* x2 = (const float*)d_in[2];
  const float* w = (const float*)d_in[3];
  const int* repeats = (const int*)d_in[4];
  float* out = (float*)d_out;

  IrrepsIndexedLinear_39161511805249_kernel<<<GRID_BLOCKS, 256, 0, stream>>>(
      x0, x1, x2, w, repeats, out);
}